// Round 18
// baseline (397.455 us; speedup 1.0000x reference)
//
#include <hip/hip_runtime.h>

#define DF    128   // feature dim
#define TPB   64    // nodes per tile
#define CAPT  352   // per-tile bucket capacity (mean 256, +6 sigma)

typedef __attribute__((ext_vector_type(8))) short short8;
typedef __attribute__((ext_vector_type(4))) float f32x4;
typedef __attribute__((ext_vector_type(2))) float f32x2;

__device__ __forceinline__ unsigned short f2bf(float x) {
    unsigned u = __float_as_uint(x);
    u = (u + 0x7FFFu + ((u >> 16) & 1u)) >> 16;   // RNE
    return (unsigned short)u;
}
__device__ __forceinline__ unsigned pack2bf(float a, float b) {
    return (unsigned)f2bf(a) | ((unsigned)f2bf(b) << 16);
}

struct AllParams {
    const float* msg[4];
    const float* Wm[4];
    float*       outp[4];
    float*       ntp[4];   // mask accumulation target (nt6/nt6/nt8/nt8)
    int eb[4];
    int N[4];
    int tcnt_[4];  // tiles per type
    int cumT[4];   // tile-id base per type
    int cumB[5];   // cumulative BLOCK counts (2 tiles/block); cumB[4] = grid
};

// ===========================================================================
// One-pass build: per-tile buckets, row packed in high bits.
// bucket entry = gid | (dst & 63) << 26
// ===========================================================================
__global__ void __launch_bounds__(256) build_kernel(
    const int* __restrict__ ei66, const int* __restrict__ ei86,
    const int* __restrict__ ei68, const int* __restrict__ ei88,
    int E66, int E86, int E68, int E88,
    int t6, int t8, int* __restrict__ tcnt, int* __restrict__ buckets)
{
    int Etot = E66 + E86 + E68 + E88;
    for (int gid = blockIdx.x * 256 + threadIdx.x; gid < Etot;
         gid += gridDim.x * 256) {
        int le = gid, ct, dst;
        if (le < E66)               { dst = ei66[2 * le + 1]; ct = 0; }
        else if ((le -= E66) < E86) { dst = ei86[2 * le + 1]; ct = t6; }
        else if ((le -= E86) < E68) { dst = ei68[2 * le + 1]; ct = 2 * t6; }
        else { le -= E68;             dst = ei88[2 * le + 1]; ct = 2 * t6 + t8; }
        int gtile = ct + (dst >> 6);
        int pos = atomicAdd(tcnt + gtile, 1);
        if (pos < CAPT)
            buckets[(size_t)gtile * CAPT + pos] =
                (int)((unsigned)gid | (((unsigned)(dst & 63)) << 26));
    }
}

// ===========================================================================
// Fused gather+MFMA: 512 threads = 2 concurrent 64-node tiles per block.
// Per tile: stage bucket -> in-LDS counting sort by row -> SCALARIZED
// depth-4 load pipeline: ids for 64 slots loaded into one per-lane VGPR
// (1 ds_read / 8 batches, double-buffered), per-edge = v_readlane -> SGPR,
// SALU row bits, and global_load_dwordx2 with SGPR-pair base + lane voff.
// Hand-counted vmcnt(24). Then swizzled bf16 flush -> MFMA -> mean ->
// coalesced store -> mask contribution via atomicAdd.
// Swizzle: element k of row m at short idx m*128 + (((k>>3)^(m&7))<<3)+(k&7)
// ===========================================================================
__global__ void __launch_bounds__(512, 4) gather_mfma_kernel(
    const int* __restrict__ tcnt, const int* __restrict__ buckets, AllParams P)
{
    __shared__ alignas(16) short Wt[DF * DF];        // 32 KB, swizzled W^T
    __shared__ alignas(16) short At[8][16 * DF];     // 32 KB, per-wave A-tiles
    __shared__ int raw_s[2][CAPT];                   // 2.75 KB
    __shared__ int eids[2][CAPT];                    // 2.75 KB (row-sorted)
    __shared__ int pref[2][TPB + 1];                 // row prefix
    __shared__ int cur[2][TPB];                      // scatter cursors

    const int t    = threadIdx.x;
    const int lane = t & 63;
    const int w    = t >> 6;        // 0..7
    const int hf   = w >> 2;        // tile half 0/1
    const int tl   = t & 255;       // thread within half
    const int wl   = w & 3;         // wave within half
    const int l15  = lane & 15;
    const int lg   = lane >> 4;
    short* Atw = At[w];

    const int bb = blockIdx.x;
    const int ty = (bb >= P.cumB[2]) ? ((bb >= P.cumB[3]) ? 3 : 2)
                                     : ((bb >= P.cumB[1]) ? 1 : 0);
    const float* msg = P.msg[ty];
    const int ebase = P.eb[ty], N = P.N[ty];
    const int tile  = (bb - P.cumB[ty]) * 2 + hf;
    const bool act  = (tile < P.tcnt_[ty]);
    const int n0    = tile * TPB;

    // ---- stage swizzled bf16 W^T (all 8 waves) ----
    {
        const float* Wm = P.Wm[ty];
        for (int idx = t; idx < 2048; idx += 512) {
            int k0 = (idx >> 5) << 1;        // even k
            int ng = (idx & 31) << 2;        // n group base
            float4 wa = *(const float4*)(Wm + (size_t)k0 * DF + ng);
            float4 wb = *(const float4*)(Wm + (size_t)(k0 + 1) * DF + ng);
            float wav[4] = {wa.x, wa.y, wa.z, wa.w};
            float wbv[4] = {wb.x, wb.y, wb.z, wb.w};
            int cb = k0 >> 3, kl = k0 & 7;
            #pragma unroll
            for (int j = 0; j < 4; ++j) {
                int n = ng + j;
                int chunk = cb ^ (n & 7);
                *(unsigned*)(Wt + n * DF + chunk * 8 + kl) =
                    pack2bf(wav[j], wbv[j]);
            }
        }
    }

    // ---- stage bucket + counting sort by row ----
    int tot_all = 0;
    if (act) {
        tot_all = tcnt[P.cumT[ty] + tile];
        if (tot_all > CAPT) tot_all = CAPT;   // overflow clamp (prob ~1e-6)
    }
    if (tl <= TPB) pref[hf][tl] = 0;
    __syncthreads();
    if (act) {
        const int* bk = buckets + (size_t)(P.cumT[ty] + tile) * CAPT;
        for (int i = tl; i < tot_all; i += 256) {
            int v = bk[i];
            raw_s[hf][i] = v;
            atomicAdd(&pref[hf][(((unsigned)v >> 26) & 63u) + 1], 1);
        }
    }
    __syncthreads();
    if (wl == 0) {                      // wave-parallel inclusive scan
        int v = (lane < TPB) ? pref[hf][lane + 1] : 0;
        #pragma unroll
        for (int off = 1; off < 64; off <<= 1) {
            int u = __shfl_up(v, off);
            if (lane >= off) v += u;
        }
        if (lane < TPB) pref[hf][lane + 1] = v;
    }
    __syncthreads();
    if (tl < TPB) cur[hf][tl] = pref[hf][tl];
    __syncthreads();
    if (act) {
        for (int i = tl; i < tot_all; i += 256) {
            int v = raw_s[hf][i];
            int p = atomicAdd(&cur[hf][((unsigned)v >> 26) & 63u], 1);
            eids[hf][p] = v;
        }
    }
    __syncthreads();

    const int wrow0 = wl * 16;
    const int lbase = pref[hf][wrow0];
    const int tot   = pref[hf][wrow0 + 16] - lbase;
    int   curr = wrow0;
    float ax = 0.f, ay = 0.f;
    const int voff = lane * 8;          // byte offset within a msg row

#define FLUSHR() {                                                            \
    int lr_ = curr & 15;                                                      \
    *(unsigned*)(Atw + lr_ * DF + ((((lane >> 2) ^ (lr_ & 7))) << 3)          \
                 + ((lane & 3) << 1)) = pack2bf(ax, ay);                      \
    ax = 0.f; ay = 0.f; ++curr; }

#define CONSB(vX, rwX, sb) { _Pragma("unroll")                                \
    for (int j = 0; j < 8; ++j) {                                             \
        if ((sb) + j < tot) {                                                 \
            int rl = wrow0 + ((rwX >> (4*j)) & 15);                           \
            while (curr < rl) FLUSHR();                                       \
            ax += vX[j][0]; ay += vX[j][1]; } } }

    // load 64 slot-ids of chunk c into one per-lane register (1 ds_read)
#define LDVID(vidX, c) {                                                      \
    int ls_ = (c) * 64 + lane; if (ls_ >= tot) ls_ = tot - 1;                 \
    vidX = eids[hf][lbase + ls_]; }

    // issue batch: k_ = uniform batch-in-chunk (0..7). Per edge: readlane ->
    // SGPR id, SALU row bits, global_load with SGPR-pair base + lane voff.
#define ISSUE_RL(vX, rwX, vidX, k_) {                                         \
    rwX = 0;                                                                  \
    _Pragma("unroll")                                                         \
    for (int j = 0; j < 8; ++j) {                                             \
        int es = __builtin_amdgcn_readlane(vidX, (k_) * 8 + j);               \
        rwX |= (((es >> 26) & 15)) << (4 * j);                                \
        const float* bp = msg + (size_t)((es & 0x03FFFFFF) - ebase) * DF;     \
        asm volatile("global_load_dwordx2 %0, %1, %2"                         \
                     : "=v"(vX[j]) : "v"(voff), "s"(bp)); } }

    // issue batch bi (chunk-register maintenance folded in)
#define ISSUEB(vX, rwX, bi) {                                                 \
    int k_ = (bi) & 7;                                                        \
    if (k_ == 0) { vidC = vidN; LDVID(vidN, ((bi) >> 3) + 1) }                \
    ISSUE_RL(vX, rwX, vidC, k_) }

#define WAITC(n) { asm volatile("s_waitcnt vmcnt(" #n ")");                   \
    __builtin_amdgcn_sched_barrier(0); }

    if (tot > 0) {
        int vidC, vidN;
        LDVID(vidC, 0)
        LDVID(vidN, 1)
        f32x2 v0[8], v1[8], v2[8], v3[8];
        int rw0, rw1, rw2, rw3;
        ISSUE_RL(v0, rw0, vidC, 0)
        ISSUE_RL(v1, rw1, vidC, 1)
        ISSUE_RL(v2, rw2, vidC, 2)
        ISSUE_RL(v3, rw3, vidC, 3)
        const int nb = (tot + 7) >> 3;
        int ib = 0;
        while (true) {
            WAITC(24) CONSB(v0, rw0, ib * 8)
            if (++ib >= nb) break;
            ISSUEB(v0, rw0, ib + 3)
            WAITC(24) CONSB(v1, rw1, ib * 8)
            if (++ib >= nb) break;
            ISSUEB(v1, rw1, ib + 3)
            WAITC(24) CONSB(v2, rw2, ib * 8)
            if (++ib >= nb) break;
            ISSUEB(v2, rw2, ib + 3)
            WAITC(24) CONSB(v3, rw3, ib * 8)
            if (++ib >= nb) break;
            ISSUEB(v3, rw3, ib + 3)
        }
        WAITC(0)   // drain before any register reuse (WAW with in-flight)
    }
    while (curr < wrow0 + 16) FLUSHR();
#undef FLUSHR
#undef CONSB
#undef LDVID
#undef ISSUE_RL
#undef ISSUEB
#undef WAITC

    // ---------------- MFMA: wave's 16 rows x 128 cols ------------------
    // A(m,k): m=lane&15, k=32*kk+8*lg+j ; B(k,n): n=lane&15, same k.
    // D: col=lane&15, row=lg*4+reg.
    f32x4 acc[8];
    #pragma unroll
    for (int j = 0; j < 8; ++j) acc[j] = (f32x4){0.f, 0.f, 0.f, 0.f};

    #pragma unroll
    for (int kk = 0; kk < 4; ++kk) {
        int c = kk * 4 + lg;
        short8 av = *(const short8*)(Atw + l15 * DF + ((c ^ (l15 & 7)) << 3));
        #pragma unroll
        for (int j = 0; j < 8; ++j) {
            int n = j * 16 + l15;
            short8 bv = *(const short8*)(Wt + n * DF + ((c ^ (n & 7)) << 3));
            acc[j] = __builtin_amdgcn_mfma_f32_16x16x32_bf16(
                av, bv, acc[j], 0, 0, 0);
        }
    }

    // mean on f32 accumulators ((sum@W)/deg == (sum/deg)@W)
    #pragma unroll
    for (int q = 0; q < 4; ++q) {
        int lrow = wrow0 + lg * 4 + q;
        int dg = pref[hf][lrow + 1] - pref[hf][lrow];
        float inv = (dg > 0) ? (1.0f / (float)dg) : 0.0f;
        #pragma unroll
        for (int j = 0; j < 8; ++j) acc[j][q] *= inv;
    }

    // ------------- store: LDS transpose -> coalesced float4 -----------
    float* fA = (float*)Atw;           // wave-private scratch (4096B)
    float* outp = P.outp[ty];
    #pragma unroll
    for (int h = 0; h < 2; ++h) {
        if ((lg >> 1) == h) {
            int lr = (lg & 1) << 2;
            #pragma unroll
            for (int q = 0; q < 4; ++q)
                #pragma unroll
                for (int j = 0; j < 8; ++j)
                    fA[(lr + q) * DF + j * 16 + l15] = acc[j][q];
        }
        asm volatile("" ::: "memory");
        #pragma unroll
        for (int rr = 0; rr < 4; ++rr) {
            int lrh  = 2 * rr + (lane >> 5);
            int node = n0 + wrow0 + 8 * h + lrh;
            float4 x = *(const float4*)(fA + lrh * DF + (lane & 31) * 4);
            if (act && node < N)
                *(float4*)(outp + (size_t)node * 256 + (lane & 31) * 4) = x;
        }
        asm volatile("" ::: "memory");
    }

    // ------------- mask contribution: nt[node] += (deg>0) --------------
    if (act && tl < TPB) {
        int node = n0 + tl;
        if (node < N) {
            int dg = pref[hf][tl + 1] - pref[hf][tl];
            if (dg > 0) atomicAdd(P.ntp[ty] + node, 1.0f);
        }
    }
}

extern "C" void kernel_launch(void* const* d_in, const int* in_sizes, int n_in,
                              void* d_out, int out_size, void* d_ws, size_t ws_size,
                              hipStream_t stream)
{
    const float* msg66 = (const float*)d_in[0];
    const float* msg68 = (const float*)d_in[1];
    const float* msg86 = (const float*)d_in[2];
    const float* msg88 = (const float*)d_in[3];
    const float* W66   = (const float*)d_in[4];
    const float* W68   = (const float*)d_in[5];
    const float* W86   = (const float*)d_in[6];
    const float* W88   = (const float*)d_in[7];
    const int*   ei66  = (const int*)d_in[8];
    const int*   ei68  = (const int*)d_in[9];
    const int*   ei86  = (const int*)d_in[10];
    const int*   ei88  = (const int*)d_in[11];

    int E66 = in_sizes[8]  / 2;
    int E68 = in_sizes[9]  / 2;
    int E86 = in_sizes[10] / 2;
    int E88 = in_sizes[11] / 2;
    int Etot = E66 + E86 + E68 + E88;

    size_t S  = (size_t)out_size / 257;       // out = 257*(N6+N8)
    int    N6 = (int)(S / 2);
    int    N8 = (int)(S - S / 2);

    float* out  = (float*)d_out;
    float* out6 = out;                          // (N6, 2, 128)
    float* out8 = out + (size_t)N6 * 256;       // (N8, 2, 128)
    float* nt6  = out + (size_t)(N6 + N8) * 256;
    float* nt8  = nt6 + N6;

    int t6 = (N6 + TPB - 1) / TPB, t8 = (N8 + TPB - 1) / TPB;
    int T  = 2 * t6 + 2 * t8;                   // total tiles

    int* tcnt    = (int*)d_ws;                  // [T]
    int* buckets = tcnt + T;                    // [T * CAPT] (~8.8 MB)

    hipMemsetAsync(tcnt, 0, (size_t)T * sizeof(int), stream);
    hipMemsetAsync(nt6, 0, (size_t)(N6 + N8) * sizeof(float), stream);

    int eg = (Etot + 255) / 256;
    if (eg > 4096) eg = 4096;
    build_kernel<<<dim3(eg), dim3(256), 0, stream>>>(
        ei66, ei86, ei68, ei88, E66, E86, E68, E88, t6, t8, tcnt, buckets);

    int b6 = (t6 + 1) / 2, b8 = (t8 + 1) / 2;
    AllParams P;
    P.msg[0] = msg66; P.Wm[0] = W66; P.outp[0] = out6;       P.eb[0] = 0;               P.N[0] = N6; P.tcnt_[0] = t6;
    P.msg[1] = msg86; P.Wm[1] = W86; P.outp[1] = out6 + 128; P.eb[1] = E66;             P.N[1] = N6; P.tcnt_[1] = t6;
    P.msg[2] = msg68; P.Wm[2] = W68; P.outp[2] = out8;       P.eb[2] = E66 + E86;       P.N[2] = N8; P.tcnt_[2] = t8;
    P.msg[3] = msg88; P.Wm[3] = W88; P.outp[3] = out8 + 128; P.eb[3] = E66 + E86 + E68; P.N[3] = N8; P.tcnt_[3] = t8;
    P.ntp[0] = nt6; P.ntp[1] = nt6; P.ntp[2] = nt8; P.ntp[3] = nt8;
    P.cumT[0] = 0;
    P.cumT[1] = t6;
    P.cumT[2] = 2 * t6;
    P.cumT[3] = 2 * t6 + t8;
    P.cumB[0] = 0;
    P.cumB[1] = b6;
    P.cumB[2] = 2 * b6;
    P.cumB[3] = 2 * b6 + b8;
    P.cumB[4] = 2 * b6 + 2 * b8;

    gather_mfma_kernel<<<dim3(P.cumB[4]), dim3(512), 0, stream>>>(
        tcnt, buckets, P);
}